// Round 9
// baseline (2454.546 us; speedup 1.0000x reference)
//
#include <hip/hip_runtime.h>

typedef __attribute__((ext_vector_type(8))) short short8;
typedef __attribute__((ext_vector_type(4))) float f32x4;

#define NSTEP 63
#define DZ 256
#define DX 64
#define DH 1024
#define SLOTF 1048576   // floats per exchange slot: 32 groups x 4 dh x 8192

__device__ __forceinline__ unsigned short f2bf(float f){
  unsigned u = __builtin_bit_cast(unsigned, f);
  u += 0x7fffu + ((u >> 16) & 1u);
  return (unsigned short)(u >> 16);
}
__device__ __forceinline__ float bf2f(unsigned short h){
  return __builtin_bit_cast(float, (unsigned)h << 16);
}
__device__ __forceinline__ void split_bf(float v, unsigned short& h, unsigned short& l){
  h = f2bf(v);
  l = f2bf(v - bf2f(h));
}
__device__ __forceinline__ float tanh_fast(float x){
  float e = __expf(2.0f * x);
  return 1.0f - 2.0f / (e + 1.0f);
}
__device__ __forceinline__ unsigned pk2(float a, float b){
  int r; asm("v_cvt_pk_bf16_f32 %0, %1, %2" : "=v"(r) : "v"(a), "v"(b));
  return (unsigned)r;
}
__device__ __forceinline__ void pack4(const float* v, unsigned long long& hi,
                                      unsigned long long& lo){
  unsigned h0 = pk2(v[0], v[1]), h1 = pk2(v[2], v[3]);
  float f0 = __builtin_bit_cast(float, h0 << 16);
  float f1 = __builtin_bit_cast(float, h0 & 0xffff0000u);
  float f2 = __builtin_bit_cast(float, h1 << 16);
  float f3 = __builtin_bit_cast(float, h1 & 0xffff0000u);
  unsigned l0 = pk2(v[0] - f0, v[1] - f1), l1 = pk2(v[2] - f2, v[3] - f3);
  hi = (unsigned long long)h0 | ((unsigned long long)h1 << 32);
  lo = (unsigned long long)l0 | ((unsigned long long)l1 << 32);
}

// Swizzled LDS access (XOR byte ^= (row&7)<<4).
template<int ROWB>
__device__ __forceinline__ short8 ldsA(const short* buf, int row, int k0){
  int byte = row * ROWB + k0 * 2;
  byte ^= ((row & 7) << 4);
  return *reinterpret_cast<const short8*>(reinterpret_cast<const char*>(buf) + byte);
}
template<int ROWB>
__device__ __forceinline__ void ldsW64(short* buf, int row, int col, unsigned long long v){
  int byte = row * ROWB + col * 2;
  byte ^= ((row & 7) << 4);
  *reinterpret_cast<unsigned long long*>(reinterpret_cast<char*>(buf) + byte) = v;
}
template<int ROWB>
__device__ __forceinline__ void ldsW16(short* buf, int row, int col, unsigned short v){
  int byte = row * ROWB + col * 2;
  byte ^= ((row & 7) << 4);
  *reinterpret_cast<short*>(reinterpret_cast<char*>(buf) + byte) = (short)v;
}

#define MFMA(a, b, c) __builtin_amdgcn_mfma_f32_16x16x32_bf16((a), (b), (c), 0, 0, 0)

// ---------------------------------------------------------------------------
// Reformat weights into hi/lo bf16 MFMA fragment pairs (validated r3/r5/r8):
//   frag(ks,nblk,p): lane l, elem j holds W[k=32ks+8(l>>4)+j][col=16nblk+(l&15)]
//   short8 index: ((ks*NB + nblk)*2 + p)*64 + lane      (p=0 hi, p=1 lo)
// ---------------------------------------------------------------------------
__global__ void reformat_weights(const float* __restrict__ W1,
                                 const float* __restrict__ W2,
                                 const float* __restrict__ Wx,
                                 short* __restrict__ W1f,
                                 short* __restrict__ W2f,
                                 short* __restrict__ Wxf){
  int tid = blockIdx.x * 256 + threadIdx.x;
  if (tid < 32768){                       // W1: ks 0..7, nblk 0..63
    int lane = tid & 63, nblk = (tid >> 6) & 63, ks = tid >> 12;
    int k0 = ks * 32 + (lane >> 4) * 8, col = nblk * 16 + (lane & 15);
    short8 vh, vl;
    #pragma unroll
    for (int j = 0; j < 8; ++j){
      unsigned short h, l; split_bf(W1[(k0 + j) * DH + col], h, l);
      vh[j] = (short)h; vl[j] = (short)l;
    }
    int base = ((ks * 64 + nblk) * 2) * 64 + lane;
    reinterpret_cast<short8*>(W1f)[base]      = vh;
    reinterpret_cast<short8*>(W1f)[base + 64] = vl;
  } else if (tid < 65536){                // W2: ks 0..31, nblk 0..15
    int t = tid - 32768;
    int lane = t & 63, nblk = (t >> 6) & 15, ks = t >> 10;
    int k0 = ks * 32 + (lane >> 4) * 8, col = nblk * 16 + (lane & 15);
    short8 vh, vl;
    #pragma unroll
    for (int j = 0; j < 8; ++j){
      unsigned short h, l; split_bf(W2[(k0 + j) * DZ + col], h, l);
      vh[j] = (short)h; vl[j] = (short)l;
    }
    int base = ((ks * 16 + nblk) * 2) * 64 + lane;
    reinterpret_cast<short8*>(W2f)[base]      = vh;
    reinterpret_cast<short8*>(W2f)[base + 64] = vl;
  } else if (tid < 73728){                // Wx: ks 0..1, nblk 0..63
    int t = tid - 65536;
    int lane = t & 63, nblk = (t >> 6) & 63, ks = t >> 12;
    int k0 = ks * 32 + (lane >> 4) * 8, col = nblk * 16 + (lane & 15);
    short8 vh, vl;
    #pragma unroll
    for (int j = 0; j < 8; ++j){
      unsigned short h, l; split_bf(Wx[(k0 + j) * DH + col], h, l);
      vh[j] = (short)h; vl[j] = (short)l;
    }
    int base = ((ks * 64 + nblk) * 2) * 64 + lane;
    reinterpret_cast<short8*>(Wxf)[base]      = vh;
    reinterpret_cast<short8*>(Wxf)[base + 64] = vl;
  }
}

__global__ void init_sync(unsigned* __restrict__ ctrs){
  int t = threadIdx.x;
  if (t < 64) ctrs[t * 16] = 0;
}

// ---------------------------------------------------------------------------
// DH-split NeuralODE r9: 128 WGs x 1024 thr (16 waves, 4/SIMD). WG
// (rb = wg&31, dh = wg>>5) owns batch rows [32rb,+32) and DH slice [256dh,+256).
// Each wave owns ONE 16-col nblk but computes BOTH 16-row tiles with the same
// weight fragments -> per-WG weight traffic 576 KB/stage amortized over 32 rows
// (2x round 8's amortization; aggregate L2 weight stream halves to 74 MB/stage).
// Exchange via sc0/sc1 + relaxed counter (r8-proven: no L2 invalidation).
// ---------------------------------------------------------------------------
__global__ __launch_bounds__(1024, 1) void node_dh4r32(
    const float* __restrict__ z0, const float* __restrict__ tt,
    const float* __restrict__ x,
    const short* __restrict__ W1f, const short* __restrict__ W2f,
    const short* __restrict__ Wxf,
    const float* __restrict__ wt, const float* __restrict__ b1,
    const float* __restrict__ b2,
    float* part, unsigned* ctrs,
    float* __restrict__ out){

  const int wg   = blockIdx.x;
  const int dh   = wg >> 5;          // 0..3
  const int rb   = wg & 31;          // 0..31
  const int tid  = threadIdx.x;
  const int w    = tid >> 6;         // wave 0..15 = nblk/kblk owner
  const int lane = tid & 63;
  const int l15  = lane & 15;
  const int lq   = lane >> 4;

  __shared__ __align__(16) short zsh[32 * 256], zsl[32 * 256];   // 16 KB each
  __shared__ __align__(16) short hbh[32 * 256], hbl[32 * 256];   // 16 KB each
  __shared__ __align__(16) short xbh[32 * 64], xbl[32 * 64];     // 4 KB each
  __shared__ __align__(16) float b1l[256], wtl[256];

  const short8* W1v = (const short8*)W1f;
  const short8* W2v = (const short8*)W2f;
  const short8* Wxv = (const short8*)Wxf;

  if (tid < 256){ b1l[tid] = b1[dh * 256 + tid]; wtl[tid] = wt[dh * 256 + tid]; }

  // state ownership from fragment-flat index f0 = tid*8:
  //   flat f = rt*4096 + kb*256 + i*64 + lane;  row = rt*16 + (lane&15),
  //   col = kb*16 + (lane>>4)*4 + i.  8 consecutive flats: col fixed, 8 rows.
  const int f0   = tid * 8;
  const int rt0  = f0 >> 12;
  const int kb   = (f0 >> 8) & 15;
  const int qi   = (f0 >> 6) & 3;
  const int l0f  = f0 & 63;
  const int colc = kb * 16 + (l0f >> 4) * 4 + qi;
  const int rowb = rt0 * 16 + (l0f & 15);      // rows rowb .. rowb+7
  const float b2c = b2[colc];

  float zb[8], za[8];
  #pragma unroll
  for (int e = 0; e < 8; ++e){
    zb[e] = z0[(rb * 32 + rowb + e) * DZ + colc];
    za[e] = 0.f;
    unsigned short hh, ll; split_bf(zb[e], hh, ll);
    ldsW16<512>(zsh, rowb + e, colc, hh);
    ldsW16<512>(zsl, rowb + e, colc, ll);
  }

  unsigned* myctr = ctrs + rb * 16;
  unsigned target = 0;

  f32x4 cx[2];

  for (int step = 0; step < NSTEP; ++step){
    const float t0 = tt[step], t1 = tt[step + 1];
    const float hs = t1 - t0;

    { // stage x[step] (hi/lo bf16, swizzled): 1024 thr x 2 elems (32x64)
      int e  = tid * 2;
      int xr = e >> 6, xc = e & 63;
      const float* xp = x + ((size_t)step * 1024 + rb * 32 + xr) * DX + xc;
      unsigned short h0, l0s, h1, l1;
      split_bf(xp[0], h0, l0s); split_bf(xp[1], h1, l1);
      int byte = (xr * 128 + xc * 2) ^ ((xr & 7) << 4);
      *reinterpret_cast<unsigned*>(reinterpret_cast<char*>(xbh) + byte) =
          (unsigned)h0 | ((unsigned)h1 << 16);
      *reinterpret_cast<unsigned*>(reinterpret_cast<char*>(xbl) + byte) =
          (unsigned)l0s | ((unsigned)l1 << 16);
    }
    __syncthreads();

    { // x-GEMM: cx[rt] = x@Wx (nblk = w), C-init reused 4 stages
      const int nb = dh * 16 + w;
      #pragma unroll
      for (int rt = 0; rt < 2; ++rt) cx[rt] = f32x4{0.f, 0.f, 0.f, 0.f};
      #pragma unroll
      for (int ks = 0; ks < 2; ++ks){
        int fi = ((ks * 64 + nb) * 2) * 64 + lane;
        short8 wh = Wxv[fi], wl = Wxv[fi + 64];
        #pragma unroll
        for (int rt = 0; rt < 2; ++rt){
          short8 axh = ldsA<128>(xbh, rt * 16 + l15, ks * 32 + lq * 8);
          short8 axl = ldsA<128>(xbl, rt * 16 + l15, ks * 32 + lq * 8);
          cx[rt] = MFMA(wh, axh, cx[rt]);
          cx[rt] = MFMA(wl, axh, cx[rt]);
          cx[rt] = MFMA(wh, axl, cx[rt]);
        }
      }
    }

    #pragma unroll 1
    for (int s = 0; s < 4; ++s){
      const float ts = (s == 0) ? t0 : ((s == 3) ? t1 : t0 + 0.5f * hs);

      // ---- GEMM1: acc[rt] = z @ W1[:, nblk], weights shared across rt ----
      f32x4 acc0 = cx[0], acc1 = cx[1];
      {
        const int nb = dh * 16 + w;
        short8 cwh, cwl, nwh, nwl;
        { int fi = (nb * 2) * 64 + lane; cwh = W1v[fi]; cwl = W1v[fi + 64]; }
        #pragma unroll 1
        for (int ks = 0; ks < 8; ++ks){
          short8 az0h = ldsA<512>(zsh, l15,      ks * 32 + lq * 8);
          short8 az0l = ldsA<512>(zsl, l15,      ks * 32 + lq * 8);
          short8 az1h = ldsA<512>(zsh, 16 + l15, ks * 32 + lq * 8);
          short8 az1l = ldsA<512>(zsl, 16 + l15, ks * 32 + lq * 8);
          if (ks < 7){
            int fi = (((ks + 1) * 64 + nb) * 2) * 64 + lane;
            nwh = W1v[fi]; nwl = W1v[fi + 64];
          }
          acc0 = MFMA(cwh, az0h, acc0); acc0 = MFMA(cwl, az0h, acc0); acc0 = MFMA(cwh, az0l, acc0);
          acc1 = MFMA(cwh, az1h, acc1); acc1 = MFMA(cwl, az1h, acc1); acc1 = MFMA(cwh, az1l, acc1);
          cwh = nwh; cwl = nwl;
        }
      }
      // epilogue: bias + tanh, pack, b64 LDS writes (local h slice)
      {
        const int cb = w * 16 + lq * 4;
        f32x4 b1v = *reinterpret_cast<const f32x4*>(&b1l[cb]);
        f32x4 wtv = *reinterpret_cast<const f32x4*>(&wtl[cb]);
        float v[4];
        unsigned long long hi, lo;
        #pragma unroll
        for (int i = 0; i < 4; ++i) v[i] = tanh_fast(acc0[i] + b1v[i] + ts * wtv[i]);
        pack4(v, hi, lo);
        ldsW64<512>(hbh, l15, cb, hi);
        ldsW64<512>(hbl, l15, cb, lo);
        #pragma unroll
        for (int i = 0; i < 4; ++i) v[i] = tanh_fast(acc1[i] + b1v[i] + ts * wtv[i]);
        pack4(v, hi, lo);
        ldsW64<512>(hbh, 16 + l15, cb, hi);
        ldsW64<512>(hbl, 16 + l15, cb, lo);
      }
      __syncthreads();   // h slice ready

      // ---- GEMM2 partial: k_dh = h_slice @ W2[k-slice, kblk=w] ----
      f32x4 p0 = {0.f, 0.f, 0.f, 0.f}, p1 = {0.f, 0.f, 0.f, 0.f};
      {
        short8 cwh, cwl, nwh, nwl;
        { int fi = ((dh * 8 * 16 + w) * 2) * 64 + lane; cwh = W2v[fi]; cwl = W2v[fi + 64]; }
        #pragma unroll 1
        for (int ks = 0; ks < 8; ++ks){
          short8 ah0h = ldsA<512>(hbh, l15,      ks * 32 + lq * 8);
          short8 ah0l = ldsA<512>(hbl, l15,      ks * 32 + lq * 8);
          short8 ah1h = ldsA<512>(hbh, 16 + l15, ks * 32 + lq * 8);
          short8 ah1l = ldsA<512>(hbl, 16 + l15, ks * 32 + lq * 8);
          if (ks < 7){
            int fi = (((dh * 8 + ks + 1) * 16 + w) * 2) * 64 + lane;
            nwh = W2v[fi]; nwl = W2v[fi + 64];
          }
          p0 = MFMA(cwh, ah0h, p0); p0 = MFMA(cwl, ah0h, p0); p0 = MFMA(cwh, ah0l, p0);
          p1 = MFMA(cwh, ah1h, p1); p1 = MFMA(cwl, ah1h, p1); p1 = MFMA(cwh, ah1l, p1);
          cwh = nwh; cwl = nwl;
        }
      }

      // ---- exchange partials: fragment-flat, sc0 sc1, base+offset stores ----
      const int g = step * 4 + s;
      float* slot = part + ((g & 1) ? (size_t)SLOTF : 0) + (size_t)rb * 32768;
      {
        float* st0 = slot + dh * 8192 +        w * 256 + lane;   // rt=0
        float* st1 = st0 + 4096;                                 // rt=1
        asm volatile(
          "global_store_dword %0, %2, off sc0 sc1\n\t"
          "global_store_dword %0, %3, off offset:256 sc0 sc1\n\t"
          "global_store_dword %0, %4, off offset:512 sc0 sc1\n\t"
          "global_store_dword %0, %5, off offset:768 sc0 sc1\n\t"
          "global_store_dword %1, %6, off sc0 sc1\n\t"
          "global_store_dword %1, %7, off offset:256 sc0 sc1\n\t"
          "global_store_dword %1, %8, off offset:512 sc0 sc1\n\t"
          "global_store_dword %1, %9, off offset:768 sc0 sc1"
          :: "v"(st0), "v"(st1),
             "v"(p0[0]), "v"(p0[1]), "v"(p0[2]), "v"(p0[3]),
             "v"(p1[0]), "v"(p1[1]), "v"(p1[2]), "v"(p1[3])
          : "memory");
      }
      asm volatile("s_waitcnt vmcnt(0)" ::: "memory");
      __syncthreads();                 // all stores at coherence point
      target += 4;
      if (tid == 0){
        __hip_atomic_fetch_add(myctr, 1u, __ATOMIC_RELAXED, __HIP_MEMORY_SCOPE_AGENT);
        while (__hip_atomic_load(myctr, __ATOMIC_RELAXED, __HIP_MEMORY_SCOPE_AGENT) < target)
          __builtin_amdgcn_s_sleep(1);
      }
      __syncthreads();                 // all 4 partials visible

      // read 4 slots: 8 contiguous floats per thread per slot (base+offset)
      f32x4 v00, v01, v10, v11, v20, v21, v30, v31;
      {
        const float* lp0 = slot + tid * 8;
        const float* lp1 = lp0 + 8192;
        const float* lp2 = lp0 + 16384;
        const float* lp3 = lp0 + 24576;
        asm volatile(
          "global_load_dwordx4 %0, %8, off sc0 sc1\n\t"
          "global_load_dwordx4 %1, %8, off offset:16 sc0 sc1\n\t"
          "global_load_dwordx4 %2, %9, off sc0 sc1\n\t"
          "global_load_dwordx4 %3, %9, off offset:16 sc0 sc1\n\t"
          "global_load_dwordx4 %4, %10, off sc0 sc1\n\t"
          "global_load_dwordx4 %5, %10, off offset:16 sc0 sc1\n\t"
          "global_load_dwordx4 %6, %11, off sc0 sc1\n\t"
          "global_load_dwordx4 %7, %11, off offset:16 sc0 sc1\n\t"
          "s_waitcnt vmcnt(0)"
          : "=&v"(v00), "=&v"(v01), "=&v"(v10), "=&v"(v11),
            "=&v"(v20), "=&v"(v21), "=&v"(v30), "=&v"(v31)
          : "v"(lp0), "v"(lp1), "v"(lp2), "v"(lp3)
          : "memory");
      }

      // reduce (fixed dh order -> bit-identical across replicas) + RK4
      const float csw = (s == 0 || s == 3) ? 1.f : 2.f;
      const float dc  = (s < 2) ? 0.5f * hs : hs;
      #pragma unroll
      for (int e = 0; e < 8; ++e){
        float s0 = (e < 4) ? v00[e] : v01[e - 4];
        float s1 = (e < 4) ? v10[e] : v11[e - 4];
        float s2 = (e < 4) ? v20[e] : v21[e - 4];
        float s3 = (e < 4) ? v30[e] : v31[e - 4];
        float kv = (((s0 + s1) + s2) + s3) + b2c;
        za[e] += csw * kv;
        float zn;
        if (s < 3){
          zn = zb[e] + dc * kv;
        } else {
          zb[e] += (hs * (1.f / 6.f)) * za[e];
          za[e] = 0.f;
          zn = zb[e];
        }
        unsigned short hh, ll; split_bf(zn, hh, ll);
        ldsW16<512>(zsh, rowb + e, colc, hh);
        ldsW16<512>(zsl, rowb + e, colc, ll);
      }
      __syncthreads();                 // z ready for next stage
    }
  }

  if (dh == 0){
    #pragma unroll
    for (int e = 0; e < 8; ++e)
      out[(rb * 32 + rowb + e) * DZ + colc] = zb[e];
  }
}

// ---------------------------------------------------------------------------
// Fallback 1: round-5 verified kernel (64 WGs x 1024 thr), needs 2.25 MB ws.
// ---------------------------------------------------------------------------
__global__ __launch_bounds__(1024, 1) void node_r5(
    const float* __restrict__ z0, const float* __restrict__ tt,
    const float* __restrict__ x,
    const short* __restrict__ W1f, const short* __restrict__ W2f,
    const short* __restrict__ Wxf,
    const float* __restrict__ wt, const float* __restrict__ b1,
    const float* __restrict__ b2, float* __restrict__ out){

  const int rb   = blockIdx.x;
  const int tid  = threadIdx.x;
  const int w    = tid >> 6;
  const int lane = tid & 63;
  const int l15  = lane & 15;
  const int lq   = lane >> 4;

  __shared__ __align__(16) short zsh[16 * DZ], zsl[16 * DZ];
  __shared__ __align__(16) short hbh[16 * DH], hbl[16 * DH];
  __shared__ __align__(16) short xbh[16 * DX], xbl[16 * DX];
  __shared__ __align__(16) float b1l[DH], wtl[DH];

  const short8* W1v = (const short8*)W1f;
  const short8* W2v = (const short8*)W2f;
  const short8* Wxv = (const short8*)Wxf;

  b1l[tid] = b1[tid];
  wtl[tid] = wt[tid];
  const f32x4 b2r = *reinterpret_cast<const f32x4*>(b2 + w * 16 + lq * 4);

  f32x4 zb, za = {0.f, 0.f, 0.f, 0.f};
  {
    zb = *reinterpret_cast<const f32x4*>(z0 + (rb * 16 + l15) * DZ + w * 16 + lq * 4);
    unsigned long long hi, lo;
    pack4((const float*)&zb, hi, lo);
    ldsW64<512>(zsh, l15, w * 16 + lq * 4, hi);
    ldsW64<512>(zsl, l15, w * 16 + lq * 4, lo);
  }

  f32x4 cx[4];

  for (int step = 0; step < NSTEP; ++step){
    const float t0 = tt[step], t1 = tt[step + 1];
    const float hs = t1 - t0;

    if (tid < 512){
      int e  = tid * 2;
      int xr = e >> 6, xc = e & 63;
      const float* xp = x + ((size_t)step * 1024 + rb * 16 + xr) * DX + xc;
      unsigned short h0, l0, h1, l1;
      split_bf(xp[0], h0, l0); split_bf(xp[1], h1, l1);
      int byte = (xr * 128 + xc * 2) ^ ((xr & 7) << 4);
      *reinterpret_cast<unsigned*>(reinterpret_cast<char*>(xbh) + byte) =
          (unsigned)h0 | ((unsigned)h1 << 16);
      *reinterpret_cast<unsigned*>(reinterpret_cast<char*>(xbl) + byte) =
          (unsigned)l0 | ((unsigned)l1 << 16);
    }
    __syncthreads();

    {
      short8 axh0 = ldsA<128>(xbh, l15, lq * 8);
      short8 axh1 = ldsA<128>(xbh, l15, 32 + lq * 8);
      short8 axl0 = ldsA<128>(xbl, l15, lq * 8);
      short8 axl1 = ldsA<128>(xbl, l15, 32 + lq * 8);
      #pragma unroll
      for (int nf = 0; nf < 4; ++nf){
        int f0 = ((      w * 4 + nf) * 2) * 64 + lane;
        int f1 = ((64 +  w * 4 + nf) * 2) * 64 + lane;
        short8 wh0 = Wxv[f0], wl0 = Wxv[f0 + 64];
        short8 wh1 = Wxv[f1], wl1 = Wxv[f1 + 64];
        f32x4 c = {0.f, 0.f, 0.f, 0.f};
        c = MFMA(wh0, axh0, c); c = MFMA(wl0, axh0, c); c = MFMA(wh0, axl0, c);
        c = MFMA(wh1, axh1, c); c = MFMA(wl1, axh1, c); c = MFMA(wh1, axl1, c);
        cx[nf] = c;
      }
    }

    #pragma unroll 1
    for (int s = 0; s < 4; ++s){
      const float ts = (s == 0) ? t0 : ((s == 3) ? t1 : t0 + 0.5f * hs);

      f32x4 acc[4];
      #pragma unroll
      for (int nf = 0; nf < 4; ++nf) acc[nf] = cx[nf];
      #pragma unroll 1
      for (int ks = 0; ks < 8; ++ks){
        short8 azh = ldsA<512>(zsh, l15, ks * 32 + lq * 8);
        short8 azl = ldsA<512>(zsl, l15, ks * 32 + lq * 8);
        #pragma unroll
        for (int nf = 0; nf < 4; ++nf){
          int fi = ((ks * 64 + w * 4 + nf) * 2) * 64 + lane;
          short8 wh = W1v[fi], wl = W1v[fi + 64];
          acc[nf] = MFMA(wh, azh, acc[nf]);
          acc[nf] = MFMA(wl, azh, acc[nf]);
          acc[nf] = MFMA(wh, azl, acc[nf]);
        }
      }
      #pragma unroll
      for (int nf = 0; nf < 4; ++nf){
        int cb = w * 64 + nf * 16 + lq * 4;
        f32x4 b1v = *reinterpret_cast<const f32x4*>(&b1l[cb]);
        f32x4 wtv = *reinterpret_cast<const f32x4*>(&wtl[cb]);
        float v[4];
        #pragma unroll
        for (int i = 0; i < 4; ++i)
          v[i] = tanh_fast(acc[nf][i] + b1v[i] + ts * wtv[i]);
        unsigned long long hi, lo;
        pack4(v, hi, lo);
        ldsW64<2048>(hbh, l15, cb, hi);
        ldsW64<2048>(hbl, l15, cb, lo);
      }
      __syncthreads();

      f32x4 acc2 = {0.f, 0.f, 0.f, 0.f};
      short8 ahh = ldsA<2048>(hbh, l15, lq * 8);
      short8 ahl = ldsA<2048>(hbl, l15, lq * 8);
      short8 wh  = W2v[((w) * 2) * 64 + lane];
      short8 wl  = W2v[((w) * 2) * 64 + lane + 64];
      #pragma unroll 1
      for (int ks = 0; ks < 32; ++ks){
        short8 nahh, nahl, nwh, nwl;
        if (ks < 31){
          nahh = ldsA<2048>(hbh, l15, (ks + 1) * 32 + lq * 8);
          nahl = ldsA<2048>(hbl, l15, (ks + 1) * 32 + lq * 8);
          int fi = (((ks + 1) * 16 + w) * 2) * 64 + lane;
          nwh = W2v[fi]; nwl = W2v[fi + 64];
        }
        acc2 = MFMA(wh, ahh, acc2);
        acc2 = MFMA(wl, ahh, acc2);
        acc2 = MFMA(wh, ahl, acc2);
        ahh = nahh; ahl = nahl; wh = nwh; wl = nwl;
      }

      const float csw = (s == 0 || s == 3) ? 1.f : 2.f;
      const float dc  = (s < 2) ? 0.5f * hs : hs;
      float zn[4];
      #pragma unroll
      for (int i = 0; i < 4; ++i){
        float kv = acc2[i] + b2r[i];
        za[i] += csw * kv;
        if (s < 3){
          zn[i] = zb[i] + dc * kv;
        } else {
          zb[i] += (hs * (1.f / 6.f)) * za[i];
          za[i] = 0.f;
          zn[i] = zb[i];
        }
      }
      unsigned long long hi, lo;
      pack4(zn, hi, lo);
      ldsW64<512>(zsh, l15, w * 16 + lq * 4, hi);
      ldsW64<512>(zsl, l15, w * 16 + lq * 4, lo);
      __syncthreads();
    }
  }

  *reinterpret_cast<f32x4*>(out + (rb * 16 + l15) * DZ + w * 16 + lq * 4) = zb;
}

// ---------------------------------------------------------------------------
// Fallback 2: round-2 verified fp32 VALU kernel (no workspace).
// ---------------------------------------------------------------------------
__global__ __launch_bounds__(512) void node_f32(
    const float* __restrict__ z0, const float* __restrict__ tt,
    const float* __restrict__ x,
    const float* __restrict__ W1, const float* __restrict__ Wx,
    const float* __restrict__ wt, const float* __restrict__ b1,
    const float* __restrict__ W2, const float* __restrict__ b2,
    float* __restrict__ out){
  const int wg = blockIdx.x, t = threadIdx.x;
  const int c0 = t, c1 = t + 512, c2 = t & 255, r0 = (t >> 8) * 4;
  __shared__ __align__(16) float zshm[8][260];
  __shared__ __align__(16) float hshm[8][1028];
  __shared__ __align__(16) float xshm[8][68];
  const float b1c0 = b1[c0], b1c1 = b1[c1], wtc0 = wt[c0], wtc1 = wt[c1], b2c = b2[c2];
  float zb[4], za[4];
  #pragma unroll
  for (int i = 0; i < 4; ++i){
    zb[i] = z0[(wg * 8 + r0 + i) * DZ + c2]; za[i] = 0.f; zshm[r0 + i][c2] = zb[i];
  }
  float cx0[8], cx1[8];
  for (int step = 0; step < NSTEP; ++step){
    const float t0 = tt[step], t1 = tt[step + 1], hs = t1 - t0;
    { int xr = t >> 6, xc = t & 63;
      xshm[xr][xc] = x[((size_t)step * 1024 + wg * 8 + xr) * DX + xc]; }
    __syncthreads();
    #pragma unroll
    for (int r = 0; r < 8; ++r){ cx0[r] = 0.f; cx1[r] = 0.f; }
    for (int k0 = 0; k0 < DX; k0 += 4){
      f32x4 xr4[8];
      #pragma unroll
      for (int r = 0; r < 8; ++r) xr4[r] = *(const f32x4*)&xshm[r][k0];
      float w0[4], w1[4];
      #pragma unroll
      for (int j = 0; j < 4; ++j){ w0[j] = Wx[(k0 + j) * DH + c0]; w1[j] = Wx[(k0 + j) * DH + c1]; }
      #pragma unroll
      for (int j = 0; j < 4; ++j)
        #pragma unroll
        for (int r = 0; r < 8; ++r){
          cx0[r] = fmaf(xr4[r][j], w0[j], cx0[r]); cx1[r] = fmaf(xr4[r][j], w1[j], cx1[r]); }
    }
    #pragma unroll 1
    for (int s = 0; s < 4; ++s){
      const float ts = (s == 0) ? t0 : ((s == 3) ? t1 : t0 + 0.5f * hs);
      float a0[8], a1[8];
      #pragma unroll
      for (int r = 0; r < 8; ++r){ a0[r] = cx0[r]; a1[r] = cx1[r]; }
      for (int k0 = 0; k0 < DZ; k0 += 4){
        f32x4 zr4[8];
        #pragma unroll
        for (int r = 0; r < 8; ++r) zr4[r] = *(const f32x4*)&zshm[r][k0];
        float w0[4], w1[4];
        #pragma unroll
        for (int j = 0; j < 4; ++j){ w0[j] = W1[(k0 + j) * DH + c0]; w1[j] = W1[(k0 + j) * DH + c1]; }
        #pragma unroll
        for (int j = 0; j < 4; ++j)
          #pragma unroll
          for (int r = 0; r < 8; ++r){
            a0[r] = fmaf(zr4[r][j], w0[j], a0[r]); a1[r] = fmaf(zr4[r][j], w1[j], a1[r]); }
      }
      const float bias0 = b1c0 + ts * wtc0, bias1 = b1c1 + ts * wtc1;
      #pragma unroll
      for (int r = 0; r < 8; ++r){
        hshm[r][c0] = tanh_fast(a0[r] + bias0); hshm[r][c1] = tanh_fast(a1[r] + bias1); }
      __syncthreads();
      float acc2[4] = {0.f, 0.f, 0.f, 0.f};
      for (int k0 = 0; k0 < DH; k0 += 4){
        f32x4 hr4[4];
        #pragma unroll
        for (int i = 0; i < 4; ++i) hr4[i] = *(const f32x4*)&hshm[r0 + i][k0];
        float w[4];
        #pragma unroll
        for (int j = 0; j < 4; ++j) w[j] = W2[(k0 + j) * DZ + c2];
        #pragma unroll
        for (int j = 0; j < 4; ++j)
          #pragma unroll
          for (int i = 0; i < 4; ++i) acc2[i] = fmaf(hr4[i][j], w[j], acc2[i]);
      }
      const float csw = (s == 0 || s == 3) ? 1.f : 2.f;
      const float dc = (s < 2) ? 0.5f * hs : hs;
      #pragma unroll
      for (int i = 0; i < 4; ++i){
        float kv = acc2[i] + b2c;
        za[i] += csw * kv;
        float zn;
        if (s < 3) zn = zb[i] + dc * kv;
        else { zb[i] += (hs * (1.f / 6.f)) * za[i]; za[i] = 0.f; zn = zb[i]; }
        zshm[r0 + i][c2] = zn;
      }
      __syncthreads();
    }
  }
  #pragma unroll
  for (int i = 0; i < 4; ++i) out[(wg * 8 + r0 + i) * DZ + c2] = zb[i];
}

extern "C" void kernel_launch(void* const* d_in, const int* in_sizes, int n_in,
                              void* d_out, int out_size, void* d_ws, size_t ws_size,
                              hipStream_t stream){
  const float* z0 = (const float*)d_in[0];
  const float* tt = (const float*)d_in[1];
  const float* x  = (const float*)d_in[2];
  const float* W1 = (const float*)d_in[3];
  const float* Wx = (const float*)d_in[4];
  const float* wt = (const float*)d_in[5];
  const float* b1 = (const float*)d_in[6];
  const float* W2 = (const float*)d_in[7];
  const float* b2 = (const float*)d_in[8];

  const size_t wBytes    = (size_t)(524288 + 524288 + 131072) * 2;   // 2359296
  const size_t partOff   = wBytes;
  const size_t partBytes = (size_t)2 * SLOTF * 4;                    // 8 MB
  const size_t ctrOff    = partOff + partBytes;
  const size_t need      = ctrOff + 64 * 16 * 4;

  if (ws_size >= need){
    short* W1f = (short*)d_ws;
    short* W2f = W1f + 524288;
    short* Wxf = W2f + 524288;
    float* part = (float*)((char*)d_ws + partOff);
    unsigned* ctrs = (unsigned*)((char*)d_ws + ctrOff);
    reformat_weights<<<288, 256, 0, stream>>>(W1, W2, Wx, W1f, W2f, Wxf);
    init_sync<<<1, 64, 0, stream>>>(ctrs);
    node_dh4r32<<<128, 1024, 0, stream>>>(z0, tt, x, W1f, W2f, Wxf, wt, b1, b2,
                                          part, ctrs, (float*)d_out);
  } else if (ws_size >= wBytes){
    short* W1f = (short*)d_ws;
    short* W2f = W1f + 524288;
    short* Wxf = W2f + 524288;
    reformat_weights<<<288, 256, 0, stream>>>(W1, W2, Wx, W1f, W2f, Wxf);
    node_r5<<<64, 1024, 0, stream>>>(z0, tt, x, W1f, W2f, Wxf, wt, b1, b2,
                                     (float*)d_out);
  } else {
    node_f32<<<128, 512, 0, stream>>>(z0, tt, x, W1, Wx, wt, b1, W2, b2,
                                      (float*)d_out);
  }
}

// Round 10
// 1820.088 us; speedup vs baseline: 1.3486x; 1.3486x over previous
//
#include <hip/hip_runtime.h>

typedef __attribute__((ext_vector_type(8))) short short8;
typedef __attribute__((ext_vector_type(4))) float f32x4;

#define NSTEP 63
#define DZ 256
#define DX 64
#define DH 1024
#define PART_FLOATS_PER_SLOT (64 * 4 * 4096)

__device__ __forceinline__ unsigned short f2bf(float f){
  unsigned u = __builtin_bit_cast(unsigned, f);
  u += 0x7fffu + ((u >> 16) & 1u);
  return (unsigned short)(u >> 16);
}
__device__ __forceinline__ float bf2f(unsigned short h){
  return __builtin_bit_cast(float, (unsigned)h << 16);
}
__device__ __forceinline__ void split_bf(float v, unsigned short& h, unsigned short& l){
  h = f2bf(v);
  l = f2bf(v - bf2f(h));
}
__device__ __forceinline__ float tanh_fast(float x){
  float e = __expf(2.0f * x);
  return 1.0f - 2.0f / (e + 1.0f);
}
__device__ __forceinline__ unsigned pk2(float a, float b){
  int r; asm("v_cvt_pk_bf16_f32 %0, %1, %2" : "=v"(r) : "v"(a), "v"(b));
  return (unsigned)r;
}
__device__ __forceinline__ void pack4(const float* v, unsigned long long& hi,
                                      unsigned long long& lo){
  unsigned h0 = pk2(v[0], v[1]), h1 = pk2(v[2], v[3]);
  float f0 = __builtin_bit_cast(float, h0 << 16);
  float f1 = __builtin_bit_cast(float, h0 & 0xffff0000u);
  float f2 = __builtin_bit_cast(float, h1 << 16);
  float f3 = __builtin_bit_cast(float, h1 & 0xffff0000u);
  unsigned l0 = pk2(v[0] - f0, v[1] - f1), l1 = pk2(v[2] - f2, v[3] - f3);
  hi = (unsigned long long)h0 | ((unsigned long long)h1 << 32);
  lo = (unsigned long long)l0 | ((unsigned long long)l1 << 32);
}

// sc0 sc1 ops: bypass L1+L2 to the device coherence point; no L2 invalidation
// (r7's acquire/release fences caused 537 MB/dispatch weight refetch).
__device__ __forceinline__ void st_sc(float* p, float v){
  asm volatile("global_store_dword %0, %1, off sc0 sc1" :: "v"(p), "v"(v) : "memory");
}

// Swizzled LDS access (XOR byte ^= (row&7)<<4).
template<int ROWB>
__device__ __forceinline__ short8 ldsA(const short* buf, int row, int k0){
  int byte = row * ROWB + k0 * 2;
  byte ^= ((row & 7) << 4);
  return *reinterpret_cast<const short8*>(reinterpret_cast<const char*>(buf) + byte);
}
template<int ROWB>
__device__ __forceinline__ void ldsW64(short* buf, int row, int col, unsigned long long v){
  int byte = row * ROWB + col * 2;
  byte ^= ((row & 7) << 4);
  *reinterpret_cast<unsigned long long*>(reinterpret_cast<char*>(buf) + byte) = v;
}
template<int ROWB>
__device__ __forceinline__ void ldsW16(short* buf, int row, int col, unsigned short v){
  int byte = row * ROWB + col * 2;
  byte ^= ((row & 7) << 4);
  *reinterpret_cast<short*>(reinterpret_cast<char*>(buf) + byte) = (short)v;
}

#define MFMA(a, b, c) __builtin_amdgcn_mfma_f32_16x16x32_bf16((a), (b), (c), 0, 0, 0)

// ---------------------------------------------------------------------------
// Reformat weights into hi/lo bf16 MFMA fragment pairs (validated r3/r5/r8).
// ---------------------------------------------------------------------------
__global__ void reformat_weights(const float* __restrict__ W1,
                                 const float* __restrict__ W2,
                                 const float* __restrict__ Wx,
                                 short* __restrict__ W1f,
                                 short* __restrict__ W2f,
                                 short* __restrict__ Wxf){
  int tid = blockIdx.x * 256 + threadIdx.x;
  if (tid < 32768){                       // W1: ks 0..7, nblk 0..63
    int lane = tid & 63, nblk = (tid >> 6) & 63, ks = tid >> 12;
    int k0 = ks * 32 + (lane >> 4) * 8, col = nblk * 16 + (lane & 15);
    short8 vh, vl;
    #pragma unroll
    for (int j = 0; j < 8; ++j){
      unsigned short h, l; split_bf(W1[(k0 + j) * DH + col], h, l);
      vh[j] = (short)h; vl[j] = (short)l;
    }
    int base = ((ks * 64 + nblk) * 2) * 64 + lane;
    reinterpret_cast<short8*>(W1f)[base]      = vh;
    reinterpret_cast<short8*>(W1f)[base + 64] = vl;
  } else if (tid < 65536){                // W2: ks 0..31, nblk 0..15
    int t = tid - 32768;
    int lane = t & 63, nblk = (t >> 6) & 15, ks = t >> 10;
    int k0 = ks * 32 + (lane >> 4) * 8, col = nblk * 16 + (lane & 15);
    short8 vh, vl;
    #pragma unroll
    for (int j = 0; j < 8; ++j){
      unsigned short h, l; split_bf(W2[(k0 + j) * DZ + col], h, l);
      vh[j] = (short)h; vl[j] = (short)l;
    }
    int base = ((ks * 16 + nblk) * 2) * 64 + lane;
    reinterpret_cast<short8*>(W2f)[base]      = vh;
    reinterpret_cast<short8*>(W2f)[base + 64] = vl;
  } else if (tid < 73728){                // Wx: ks 0..1, nblk 0..63
    int t = tid - 65536;
    int lane = t & 63, nblk = (t >> 6) & 63, ks = t >> 12;
    int k0 = ks * 32 + (lane >> 4) * 8, col = nblk * 16 + (lane & 15);
    short8 vh, vl;
    #pragma unroll
    for (int j = 0; j < 8; ++j){
      unsigned short h, l; split_bf(Wx[(k0 + j) * DH + col], h, l);
      vh[j] = (short)h; vl[j] = (short)l;
    }
    int base = ((ks * 64 + nblk) * 2) * 64 + lane;
    reinterpret_cast<short8*>(Wxf)[base]      = vh;
    reinterpret_cast<short8*>(Wxf)[base + 64] = vl;
  }
}

__global__ void init_sync(unsigned* __restrict__ ctrs){
  int t = threadIdx.x;
  if (t < 64) ctrs[t * 16] = 0;
}

// ---------------------------------------------------------------------------
// DH-split NeuralODE (r8 structure + W2 register-cache): 256 WGs x 512 thr.
// WG (rb = wg&63, dh = wg>>6) owns batch rows [16rb,+16), DH slice [256dh,+256).
// W2 slice per wave (8 ks x 2 kblk x hi/lo = 32 frags = 128 VGPRs) is loaded
// ONCE before the step loop -> per-WG L2 weight stream drops 576->320 KB/stage.
// Exchange via sc0/sc1 + relaxed counter (r8-proven). RK4 replicated
// bit-identically; all arithmetic identical to r8.
// ---------------------------------------------------------------------------
__global__ __launch_bounds__(512, 2) void node_dh4(
    const float* __restrict__ z0, const float* __restrict__ tt,
    const float* __restrict__ x,
    const short* __restrict__ W1f, const short* __restrict__ W2f,
    const short* __restrict__ Wxf,
    const float* __restrict__ wt, const float* __restrict__ b1,
    const float* __restrict__ b2,
    float* part, unsigned* ctrs,
    float* __restrict__ out){

  const int wg   = blockIdx.x;
  const int dh   = wg >> 6;          // 0..3
  const int rb   = wg & 63;
  const int tid  = threadIdx.x;
  const int w    = tid >> 6;         // wave 0..7
  const int lane = tid & 63;
  const int l15  = lane & 15;
  const int lq   = lane >> 4;

  __shared__ __align__(16) short zsh[16 * 256], zsl[16 * 256];   // 8 KB each
  __shared__ __align__(16) short hbh[16 * 256], hbl[16 * 256];   // 8 KB each
  __shared__ __align__(16) short xbh[16 * 64], xbl[16 * 64];     // 2 KB each
  __shared__ __align__(16) float b1l[256], wtl[256];

  const short8* W1v = (const short8*)W1f;
  const short8* W2v = (const short8*)W2f;
  const short8* Wxv = (const short8*)Wxf;

  if (tid < 256){ b1l[tid] = b1[dh * 256 + tid]; wtl[tid] = wt[dh * 256 + tid]; }

  // W2 slice register-cache: loop-invariant across all 252 stages.
  short8 w2h[8][2], w2l[8][2];
  #pragma unroll
  for (int ks = 0; ks < 8; ++ks)
    #pragma unroll
    for (int n2 = 0; n2 < 2; ++n2){
      int fi = (((dh * 8 + ks) * 16 + w * 2 + n2) * 2) * 64 + lane;
      w2h[ks][n2] = W2v[fi]; w2l[ks][n2] = W2v[fi + 64];
    }

  // state distribution by fragment-flat index (r8): thread owns col colc,
  // rows r0r, r0r+1, ..., interleaved as flats [8t, 8t+8)
  const int qq   = tid >> 3;
  const int l0   = (tid & 7) * 8;
  const int r0r  = (tid & 1) * 8;
  const int colc = (qq >> 2) * 16 + (l0 >> 4) * 4 + (qq & 3);
  const float b2c = b2[colc];

  float zb[8], za[8];
  #pragma unroll
  for (int e = 0; e < 8; ++e){
    zb[e] = z0[(rb * 16 + r0r + e) * DZ + colc];
    za[e] = 0.f;
    unsigned short hh, ll; split_bf(zb[e], hh, ll);
    ldsW16<512>(zsh, r0r + e, colc, hh);
    ldsW16<512>(zsl, r0r + e, colc, ll);
  }

  float* grpPart   = part + (size_t)rb * (4 * 4096);
  unsigned* myctr  = ctrs + rb * 16;
  unsigned target  = 0;

  f32x4 cx[2];

  for (int step = 0; step < NSTEP; ++step){
    const float t0 = tt[step], t1 = tt[step + 1];
    const float hs = t1 - t0;

    { // stage x[step] (hi/lo bf16, swizzled): 512 thr x 2 elems
      int e  = tid * 2;
      int xr = e >> 6, xc = e & 63;
      const float* xp = x + ((size_t)step * 1024 + rb * 16 + xr) * DX + xc;
      unsigned short h0, l0s, h1, l1;
      split_bf(xp[0], h0, l0s); split_bf(xp[1], h1, l1);
      int byte = (xr * 128 + xc * 2) ^ ((xr & 7) << 4);
      *reinterpret_cast<unsigned*>(reinterpret_cast<char*>(xbh) + byte) =
          (unsigned)h0 | ((unsigned)h1 << 16);
      *reinterpret_cast<unsigned*>(reinterpret_cast<char*>(xbl) + byte) =
          (unsigned)l0s | ((unsigned)l1 << 16);
    }
    __syncthreads();

    { // x-GEMM: cx = x@Wx slice (C-init for 4 stages), operand-swapped
      short8 axh0 = ldsA<128>(xbh, l15, lq * 8);
      short8 axh1 = ldsA<128>(xbh, l15, 32 + lq * 8);
      short8 axl0 = ldsA<128>(xbl, l15, lq * 8);
      short8 axl1 = ldsA<128>(xbl, l15, 32 + lq * 8);
      #pragma unroll
      for (int n2 = 0; n2 < 2; ++n2){
        int nblk = dh * 16 + w * 2 + n2;
        int f0 = ((     nblk) * 2) * 64 + lane;
        int f1 = ((64 + nblk) * 2) * 64 + lane;
        short8 wh0 = Wxv[f0], wl0 = Wxv[f0 + 64];
        short8 wh1 = Wxv[f1], wl1 = Wxv[f1 + 64];
        f32x4 c = {0.f, 0.f, 0.f, 0.f};
        c = MFMA(wh0, axh0, c); c = MFMA(wl0, axh0, c); c = MFMA(wh0, axl0, c);
        c = MFMA(wh1, axh1, c); c = MFMA(wl1, axh1, c); c = MFMA(wh1, axl1, c);
        cx[n2] = c;
      }
    }

    #pragma unroll 1
    for (int s = 0; s < 4; ++s){
      const float ts = (s == 0) ? t0 : ((s == 3) ? t1 : t0 + 0.5f * hs);

      // ---- GEMM1: acc = z @ W1[:, slice] + cx, 1-deep weight prefetch ----
      f32x4 acc[2] = {cx[0], cx[1]};
      {
        const int nb0 = dh * 16 + w * 2;
        short8 cwh[2], cwl[2], nwh[2], nwl[2];
        #pragma unroll
        for (int n2 = 0; n2 < 2; ++n2){
          int fi = ((nb0 + n2) * 2) * 64 + lane;
          cwh[n2] = W1v[fi]; cwl[n2] = W1v[fi + 64];
        }
        #pragma unroll 1
        for (int ks = 0; ks < 8; ++ks){
          short8 azh = ldsA<512>(zsh, l15, ks * 32 + lq * 8);
          short8 azl = ldsA<512>(zsl, l15, ks * 32 + lq * 8);
          if (ks < 7){
            #pragma unroll
            for (int n2 = 0; n2 < 2; ++n2){
              int fi = (((ks + 1) * 64 + nb0 + n2) * 2) * 64 + lane;
              nwh[n2] = W1v[fi]; nwl[n2] = W1v[fi + 64];
            }
          }
          #pragma unroll
          for (int n2 = 0; n2 < 2; ++n2){
            acc[n2] = MFMA(cwh[n2], azh, acc[n2]);
            acc[n2] = MFMA(cwl[n2], azh, acc[n2]);
            acc[n2] = MFMA(cwh[n2], azl, acc[n2]);
          }
          cwh[0] = nwh[0]; cwh[1] = nwh[1];
          cwl[0] = nwl[0]; cwl[1] = nwl[1];
        }
      }
      // epilogue: bias + tanh, pack, b64 LDS writes (local h slice)
      #pragma unroll
      for (int n2 = 0; n2 < 2; ++n2){
        int cb = w * 32 + n2 * 16 + lq * 4;
        f32x4 b1v = *reinterpret_cast<const f32x4*>(&b1l[cb]);
        f32x4 wtv = *reinterpret_cast<const f32x4*>(&wtl[cb]);
        float v[4];
        #pragma unroll
        for (int i = 0; i < 4; ++i)
          v[i] = tanh_fast(acc[n2][i] + b1v[i] + ts * wtv[i]);
        unsigned long long hi, lo;
        pack4(v, hi, lo);
        ldsW64<512>(hbh, l15, cb, hi);
        ldsW64<512>(hbl, l15, cb, lo);
      }
      __syncthreads();   // h slice ready

      // ---- GEMM2 partial: k_dh = h_slice @ W2[k-slice, :] — weights in regs
      f32x4 acc2[2] = {{0.f,0.f,0.f,0.f}, {0.f,0.f,0.f,0.f}};
      #pragma unroll
      for (int ks = 0; ks < 8; ++ks){
        short8 ahh = ldsA<512>(hbh, l15, ks * 32 + lq * 8);
        short8 ahl = ldsA<512>(hbl, l15, ks * 32 + lq * 8);
        #pragma unroll
        for (int n2 = 0; n2 < 2; ++n2){
          acc2[n2] = MFMA(w2h[ks][n2], ahh, acc2[n2]);
          acc2[n2] = MFMA(w2l[ks][n2], ahh, acc2[n2]);
          acc2[n2] = MFMA(w2h[ks][n2], ahl, acc2[n2]);
        }
      }

      // ---- exchange partials (fragment-flat layout, coalesced, sc0 sc1) ----
      const int g = step * 4 + s;
      float* slot = grpPart + ((g & 1) ? (size_t)PART_FLOATS_PER_SLOT : 0);
      {
        float* dst = slot + dh * 4096;
        #pragma unroll
        for (int n2 = 0; n2 < 2; ++n2)
          #pragma unroll
          for (int i = 0; i < 4; ++i){
            int flat = ((w * 2 + n2) * 4 + i) * 64 + lane;
            st_sc(dst + flat, acc2[n2][i]);
          }
      }
      asm volatile("s_waitcnt vmcnt(0)" ::: "memory");
      __syncthreads();                 // all stores at coherence point
      target += 4;
      if (tid == 0){
        __hip_atomic_fetch_add(myctr, 1u, __ATOMIC_RELAXED, __HIP_MEMORY_SCOPE_AGENT);
        while (__hip_atomic_load(myctr, __ATOMIC_RELAXED, __HIP_MEMORY_SCOPE_AGENT) < target)
          __builtin_amdgcn_s_sleep(1);
      }
      __syncthreads();                 // all 4 partials visible

      // read all 4 slots: 8 contiguous floats per thread per slot
      f32x4 v00, v01, v10, v11, v20, v21, v30, v31;
      {
        const float* pr = slot + tid * 8;
        asm volatile(
          "global_load_dwordx4 %0, %8, off sc0 sc1\n\t"
          "global_load_dwordx4 %1, %9, off sc0 sc1\n\t"
          "global_load_dwordx4 %2, %10, off sc0 sc1\n\t"
          "global_load_dwordx4 %3, %11, off sc0 sc1\n\t"
          "global_load_dwordx4 %4, %12, off sc0 sc1\n\t"
          "global_load_dwordx4 %5, %13, off sc0 sc1\n\t"
          "global_load_dwordx4 %6, %14, off sc0 sc1\n\t"
          "global_load_dwordx4 %7, %15, off sc0 sc1\n\t"
          "s_waitcnt vmcnt(0)"
          : "=&v"(v00), "=&v"(v01), "=&v"(v10), "=&v"(v11),
            "=&v"(v20), "=&v"(v21), "=&v"(v30), "=&v"(v31)
          : "v"(pr), "v"(pr + 4),
            "v"(pr + 4096), "v"(pr + 4100),
            "v"(pr + 8192), "v"(pr + 8196),
            "v"(pr + 12288), "v"(pr + 12292)
          : "memory");
      }

      // reduce (fixed dh order -> bit-identical across replicas) + RK4
      const float csw = (s == 0 || s == 3) ? 1.f : 2.f;
      const float dc  = (s < 2) ? 0.5f * hs : hs;
      #pragma unroll
      for (int e = 0; e < 8; ++e){
        float s0 = (e < 4) ? v00[e] : v01[e - 4];
        float s1 = (e < 4) ? v10[e] : v11[e - 4];
        float s2 = (e < 4) ? v20[e] : v21[e - 4];
        float s3 = (e < 4) ? v30[e] : v31[e - 4];
        float kv = (((s0 + s1) + s2) + s3) + b2c;
        za[e] += csw * kv;
        float zn;
        if (s < 3){
          zn = zb[e] + dc * kv;
        } else {
          zb[e] += (hs * (1.f / 6.f)) * za[e];
          za[e] = 0.f;
          zn = zb[e];
        }
        unsigned short hh, ll; split_bf(zn, hh, ll);
        ldsW16<512>(zsh, r0r + e, colc, hh);
        ldsW16<512>(zsl, r0r + e, colc, ll);
      }
      __syncthreads();                 // z ready for next stage
    }
  }

  if (dh == 0){
    #pragma unroll
    for (int e = 0; e < 8; ++e)
      out[(rb * 16 + r0r + e) * DZ + colc] = zb[e];
  }
}

// ---------------------------------------------------------------------------
// Fallback: round-2 verified fp32 VALU kernel (no workspace).
// ---------------------------------------------------------------------------
__global__ __launch_bounds__(512) void node_f32(
    const float* __restrict__ z0, const float* __restrict__ tt,
    const float* __restrict__ x,
    const float* __restrict__ W1, const float* __restrict__ Wx,
    const float* __restrict__ wt, const float* __restrict__ b1,
    const float* __restrict__ W2, const float* __restrict__ b2,
    float* __restrict__ out){
  const int wg = blockIdx.x, t = threadIdx.x;
  const int c0 = t, c1 = t + 512, c2 = t & 255, r0 = (t >> 8) * 4;
  __shared__ __align__(16) float zshm[8][260];
  __shared__ __align__(16) float hshm[8][1028];
  __shared__ __align__(16) float xshm[8][68];
  const float b1c0 = b1[c0], b1c1 = b1[c1], wtc0 = wt[c0], wtc1 = wt[c1], b2c = b2[c2];
  float zb[4], za[4];
  #pragma unroll
  for (int i = 0; i < 4; ++i){
    zb[i] = z0[(wg * 8 + r0 + i) * DZ + c2]; za[i] = 0.f; zshm[r0 + i][c2] = zb[i];
  }
  float cx0[8], cx1[8];
  for (int step = 0; step < NSTEP; ++step){
    const float t0 = tt[step], t1 = tt[step + 1], hs = t1 - t0;
    { int xr = t >> 6, xc = t & 63;
      xshm[xr][xc] = x[((size_t)step * 1024 + wg * 8 + xr) * DX + xc]; }
    __syncthreads();
    #pragma unroll
    for (int r = 0; r < 8; ++r){ cx0[r] = 0.f; cx1[r] = 0.f; }
    for (int k0 = 0; k0 < DX; k0 += 4){
      f32x4 xr4[8];
      #pragma unroll
      for (int r = 0; r < 8; ++r) xr4[r] = *(const f32x4*)&xshm[r][k0];
      float w0[4], w1[4];
      #pragma unroll
      for (int j = 0; j < 4; ++j){ w0[j] = Wx[(k0 + j) * DH + c0]; w1[j] = Wx[(k0 + j) * DH + c1]; }
      #pragma unroll
      for (int j = 0; j < 4; ++j)
        #pragma unroll
        for (int r = 0; r < 8; ++r){
          cx0[r] = fmaf(xr4[r][j], w0[j], cx0[r]); cx1[r] = fmaf(xr4[r][j], w1[j], cx1[r]); }
    }
    #pragma unroll 1
    for (int s = 0; s < 4; ++s){
      const float ts = (s == 0) ? t0 : ((s == 3) ? t1 : t0 + 0.5f * hs);
      float a0[8], a1[8];
      #pragma unroll
      for (int r = 0; r < 8; ++r){ a0[r] = cx0[r]; a1[r] = cx1[r]; }
      for (int k0 = 0; k0 < DZ; k0 += 4){
        f32x4 zr4[8];
        #pragma unroll
        for (int r = 0; r < 8; ++r) zr4[r] = *(const f32x4*)&zshm[r][k0];
        float w0[4], w1[4];
        #pragma unroll
        for (int j = 0; j < 4; ++j){ w0[j] = W1[(k0 + j) * DH + c0]; w1[j] = W1[(k0 + j) * DH + c1]; }
        #pragma unroll
        for (int j = 0; j < 4; ++j)
          #pragma unroll
          for (int r = 0; r < 8; ++r){
            a0[r] = fmaf(zr4[r][j], w0[j], a0[r]); a1[r] = fmaf(zr4[r][j], w1[j], a1[r]); }
      }
      const float bias0 = b1c0 + ts * wtc0, bias1 = b1c1 + ts * wtc1;
      #pragma unroll
      for (int r = 0; r < 8; ++r){
        hshm[r][c0] = tanh_fast(a0[r] + bias0); hshm[r][c1] = tanh_fast(a1[r] + bias1); }
      __syncthreads();
      float acc2[4] = {0.f, 0.f, 0.f, 0.f};
      for (int k0 = 0; k0 < DH; k0 += 4){
        f32x4 hr4[4];
        #pragma unroll
        for (int i = 0; i < 4; ++i) hr4[i] = *(const f32x4*)&hshm[r0 + i][k0];
        float w[4];
        #pragma unroll
        for (int j = 0; j < 4; ++j) w[j] = W2[(k0 + j) * DZ + c2];
        #pragma unroll
        for (int j = 0; j < 4; ++j)
          #pragma unroll
          for (int i = 0; i < 4; ++i) acc2[i] = fmaf(hr4[i][j], w[j], acc2[i]);
      }
      const float csw = (s == 0 || s == 3) ? 1.f : 2.f;
      const float dc = (s < 2) ? 0.5f * hs : hs;
      #pragma unroll
      for (int i = 0; i < 4; ++i){
        float kv = acc2[i] + b2c;
        za[i] += csw * kv;
        float zn;
        if (s < 3) zn = zb[i] + dc * kv;
        else { zb[i] += (hs * (1.f / 6.f)) * za[i]; za[i] = 0.f; zn = zb[i]; }
        zshm[r0 + i][c2] = zn;
      }
      __syncthreads();
    }
  }
  #pragma unroll
  for (int i = 0; i < 4; ++i) out[(wg * 8 + r0 + i) * DZ + c2] = zb[i];
}

extern "C" void kernel_launch(void* const* d_in, const int* in_sizes, int n_in,
                              void* d_out, int out_size, void* d_ws, size_t ws_size,
                              hipStream_t stream){
  const float* z0 = (const float*)d_in[0];
  const float* tt = (const float*)d_in[1];
  const float* x  = (const float*)d_in[2];
  const float* W1 = (const float*)d_in[3];
  const float* Wx = (const float*)d_in[4];
  const float* wt = (const float*)d_in[5];
  const float* b1 = (const float*)d_in[6];
  const float* W2 = (const float*)d_in[7];
  const float* b2 = (const float*)d_in[8];

  const size_t wBytes    = (size_t)(524288 + 524288 + 131072) * 2;   // 2359296
  const size_t partOff   = wBytes;
  const size_t partBytes = (size_t)2 * PART_FLOATS_PER_SLOT * 4;     // 8 MB
  const size_t ctrOff    = partOff + partBytes;
  const size_t need      = ctrOff + 64 * 16 * 4;

  if (ws_size >= need){
    short* W1f = (short*)d_ws;
    short* W2f = W1f + 524288;
    short* Wxf = W2f + 524288;
    float* part = (float*)((char*)d_ws + partOff);
    unsigned* ctrs = (unsigned*)((char*)d_ws + ctrOff);
    reformat_weights<<<288, 256, 0, stream>>>(W1, W2, Wx, W1f, W2f, Wxf);
    init_sync<<<1, 64, 0, stream>>>(ctrs);
    node_dh4<<<256, 512, 0, stream>>>(z0, tt, x, W1f, W2f, Wxf, wt, b1, b2,
                                      part, ctrs, (float*)d_out);
  } else {
    node_f32<<<128, 512, 0, stream>>>(z0, tt, x, W1, Wx, wt, b1, W2, b2,
                                      (float*)d_out);
  }
}

// Round 12
// 1803.431 us; speedup vs baseline: 1.3610x; 1.0092x over previous
//
#include <hip/hip_runtime.h>

typedef __attribute__((ext_vector_type(8))) short short8;
typedef __attribute__((ext_vector_type(4))) float f32x4;

#define NSTEP 63
#define DZ 256
#define DX 64
#define DH 1024
#define PART_FLOATS_PER_SLOT (64 * 4 * 4096)

__device__ __forceinline__ unsigned short f2bf(float f){
  unsigned u = __builtin_bit_cast(unsigned, f);
  u += 0x7fffu + ((u >> 16) & 1u);
  return (unsigned short)(u >> 16);
}
__device__ __forceinline__ float bf2f(unsigned short h){
  return __builtin_bit_cast(float, (unsigned)h << 16);
}
__device__ __forceinline__ void split_bf(float v, unsigned short& h, unsigned short& l){
  h = f2bf(v);
  l = f2bf(v - bf2f(h));
}
__device__ __forceinline__ float tanh_fast(float x){
  float e = __expf(2.0f * x);
  return 1.0f - 2.0f / (e + 1.0f);
}
__device__ __forceinline__ unsigned pk2(float a, float b){
  int r; asm("v_cvt_pk_bf16_f32 %0, %1, %2" : "=v"(r) : "v"(a), "v"(b));
  return (unsigned)r;
}
__device__ __forceinline__ void pack4(const float* v, unsigned long long& hi,
                                      unsigned long long& lo){
  unsigned h0 = pk2(v[0], v[1]), h1 = pk2(v[2], v[3]);
  float f0 = __builtin_bit_cast(float, h0 << 16);
  float f1 = __builtin_bit_cast(float, h0 & 0xffff0000u);
  float f2 = __builtin_bit_cast(float, h1 << 16);
  float f3 = __builtin_bit_cast(float, h1 & 0xffff0000u);
  unsigned l0 = pk2(v[0] - f0, v[1] - f1), l1 = pk2(v[2] - f2, v[3] - f3);
  hi = (unsigned long long)h0 | ((unsigned long long)h1 << 32);
  lo = (unsigned long long)l0 | ((unsigned long long)l1 << 32);
}

// sc0 sc1: bypass L1+L2 to device coherence point; no L2 invalidation (r7/r8).
__device__ __forceinline__ void st_sc(float* p, float v){
  asm volatile("global_store_dword %0, %1, off sc0 sc1" :: "v"(p), "v"(v) : "memory");
}

// Swizzled LDS access (XOR byte ^= (row&7)<<4).
template<int ROWB>
__device__ __forceinline__ short8 ldsA(const short* buf, int row, int k0){
  int byte = row * ROWB + k0 * 2;
  byte ^= ((row & 7) << 4);
  return *reinterpret_cast<const short8*>(reinterpret_cast<const char*>(buf) + byte);
}
template<int ROWB>
__device__ __forceinline__ void ldsW64(short* buf, int row, int col, unsigned long long v){
  int byte = row * ROWB + col * 2;
  byte ^= ((row & 7) << 4);
  *reinterpret_cast<unsigned long long*>(reinterpret_cast<char*>(buf) + byte) = v;
}
template<int ROWB>
__device__ __forceinline__ void ldsW16(short* buf, int row, int col, unsigned short v){
  int byte = row * ROWB + col * 2;
  byte ^= ((row & 7) << 4);
  *reinterpret_cast<short*>(reinterpret_cast<char*>(buf) + byte) = (short)v;
}

#define MFMA(a, b, c) __builtin_amdgcn_mfma_f32_16x16x32_bf16((a), (b), (c), 0, 0, 0)

// ---------------------------------------------------------------------------
// Reformat weights into hi/lo bf16 MFMA fragment pairs (validated r3/r5/r8).
// ---------------------------------------------------------------------------
__global__ void reformat_weights(const float* __restrict__ W1,
                                 const float* __restrict__ W2,
                                 const float* __restrict__ Wx,
                                 short* __restrict__ W1f,
                                 short* __restrict__ W2f,
                                 short* __restrict__ Wxf){
  int tid = blockIdx.x * 256 + threadIdx.x;
  if (tid < 32768){                       // W1: ks 0..7, nblk 0..63
    int lane = tid & 63, nblk = (tid >> 6) & 63, ks = tid >> 12;
    int k0 = ks * 32 + (lane >> 4) * 8, col = nblk * 16 + (lane & 15);
    short8 vh, vl;
    #pragma unroll
    for (int j = 0; j < 8; ++j){
      unsigned short h, l; split_bf(W1[(k0 + j) * DH + col], h, l);
      vh[j] = (short)h; vl[j] = (short)l;
    }
    int base = ((ks * 64 + nblk) * 2) * 64 + lane;
    reinterpret_cast<short8*>(W1f)[base]      = vh;
    reinterpret_cast<short8*>(W1f)[base + 64] = vl;
  } else if (tid < 65536){                // W2: ks 0..31, nblk 0..15
    int t = tid - 32768;
    int lane = t & 63, nblk = (t >> 6) & 15, ks = t >> 10;
    int k0 = ks * 32 + (lane >> 4) * 8, col = nblk * 16 + (lane & 15);
    short8 vh, vl;
    #pragma unroll
    for (int j = 0; j < 8; ++j){
      unsigned short h, l; split_bf(W2[(k0 + j) * DZ + col], h, l);
      vh[j] = (short)h; vl[j] = (short)l;
    }
    int base = ((ks * 16 + nblk) * 2) * 64 + lane;
    reinterpret_cast<short8*>(W2f)[base]      = vh;
    reinterpret_cast<short8*>(W2f)[base + 64] = vl;
  } else if (tid < 73728){                // Wx: ks 0..1, nblk 0..63
    int t = tid - 65536;
    int lane = t & 63, nblk = (t >> 6) & 63, ks = t >> 12;
    int k0 = ks * 32 + (lane >> 4) * 8, col = nblk * 16 + (lane & 15);
    short8 vh, vl;
    #pragma unroll
    for (int j = 0; j < 8; ++j){
      unsigned short h, l; split_bf(Wx[(k0 + j) * DH + col], h, l);
      vh[j] = (short)h; vl[j] = (short)l;
    }
    int base = ((ks * 64 + nblk) * 2) * 64 + lane;
    reinterpret_cast<short8*>(Wxf)[base]      = vh;
    reinterpret_cast<short8*>(Wxf)[base + 64] = vl;
  }
}

__global__ void init_sync(unsigned* __restrict__ ctrs){
  int t = threadIdx.x;
  if (t < 64) ctrs[t * 16] = 0;
}

// ---------------------------------------------------------------------------
// DH-split NeuralODE (r8 structure + REAL W2 register cache): 256 WGs x 512.
// WG (rb = wg&63, dh = wg>>6) owns rows [16rb,+16), DH slice [256dh,+256).
// __launch_bounds__(512) (no min-waves): only 1 WG/CU is ever resident
// (grid == CU count; measured occupancy 23.8% = 7.6 waves), so the previous
// (512,2) bound only capped VGPRs at 128 and made the compiler rematerialize
// the cache (r10) / spill asm loads (r11). W2 cache is loaded via VOLATILE
// vector loads: compiler-visible (waitcnt-safe) but non-rematerializable ->
// 128 VGPRs of genuinely resident weights; per-WG L2 stream 528->272 KB/stage.
// Exchange via sc0/sc1 + relaxed counter (r8-proven). Arithmetic == r8.
// ---------------------------------------------------------------------------
__global__ __launch_bounds__(512) void node_dh4(
    const float* __restrict__ z0, const float* __restrict__ tt,
    const float* __restrict__ x,
    const short* __restrict__ W1f, const short* __restrict__ W2f,
    const short* __restrict__ Wxf,
    const float* __restrict__ wt, const float* __restrict__ b1,
    const float* __restrict__ b2,
    float* part, unsigned* ctrs,
    float* __restrict__ out){

  const int wg   = blockIdx.x;
  const int dh   = wg >> 6;          // 0..3
  const int rb   = wg & 63;
  const int tid  = threadIdx.x;
  const int w    = tid >> 6;         // wave 0..7
  const int lane = tid & 63;
  const int l15  = lane & 15;
  const int lq   = lane >> 4;

  __shared__ __align__(16) short zsh[16 * 256], zsl[16 * 256];   // 8 KB each
  __shared__ __align__(16) short hbh[16 * 256], hbl[16 * 256];   // 8 KB each
  __shared__ __align__(16) short xbh[16 * 64], xbl[16 * 64];     // 2 KB each
  __shared__ __align__(16) float b1l[256], wtl[256];

  const short8* W1v = (const short8*)W1f;
  const short8* Wxv = (const short8*)Wxf;

  if (tid < 256){ b1l[tid] = b1[dh * 256 + tid]; wtl[tid] = wt[dh * 256 + tid]; }

  // W2 slice register cache: 8 ks x 2 kblk x hi/lo = 32 frags = 128 VGPRs.
  // volatile -> cannot be rematerialized into per-stage loads (r10 failure).
  short8 w2h[8][2], w2l[8][2];
  {
    const volatile short8* W2vv = (const volatile short8*)W2f;
    #pragma unroll
    for (int ks = 0; ks < 8; ++ks)
      #pragma unroll
      for (int n2 = 0; n2 < 2; ++n2){
        int fi = (((dh * 8 + ks) * 16 + w * 2 + n2) * 2) * 64 + lane;
        w2h[ks][n2] = W2vv[fi];
        w2l[ks][n2] = W2vv[fi + 64];
      }
  }

  // state distribution by fragment-flat index (r8): thread owns col colc,
  // rows r0r..r0r+7 interleaved as flats [8t, 8t+8)
  const int qq   = tid >> 3;
  const int l0   = (tid & 7) * 8;
  const int r0r  = (tid & 1) * 8;
  const int colc = (qq >> 2) * 16 + (l0 >> 4) * 4 + (qq & 3);
  const float b2c = b2[colc];

  float zb[8], za[8];
  #pragma unroll
  for (int e = 0; e < 8; ++e){
    zb[e] = z0[(rb * 16 + r0r + e) * DZ + colc];
    za[e] = 0.f;
    unsigned short hh, ll; split_bf(zb[e], hh, ll);
    ldsW16<512>(zsh, r0r + e, colc, hh);
    ldsW16<512>(zsl, r0r + e, colc, ll);
  }

  float* grpPart   = part + (size_t)rb * (4 * 4096);
  unsigned* myctr  = ctrs + rb * 16;
  unsigned target  = 0;

  f32x4 cx[2];

  for (int step = 0; step < NSTEP; ++step){
    const float t0 = tt[step], t1 = tt[step + 1];
    const float hs = t1 - t0;

    { // stage x[step] (hi/lo bf16, swizzled): 512 thr x 2 elems
      int e  = tid * 2;
      int xr = e >> 6, xc = e & 63;
      const float* xp = x + ((size_t)step * 1024 + rb * 16 + xr) * DX + xc;
      unsigned short h0, l0s, h1, l1;
      split_bf(xp[0], h0, l0s); split_bf(xp[1], h1, l1);
      int byte = (xr * 128 + xc * 2) ^ ((xr & 7) << 4);
      *reinterpret_cast<unsigned*>(reinterpret_cast<char*>(xbh) + byte) =
          (unsigned)h0 | ((unsigned)h1 << 16);
      *reinterpret_cast<unsigned*>(reinterpret_cast<char*>(xbl) + byte) =
          (unsigned)l0s | ((unsigned)l1 << 16);
    }
    __syncthreads();

    { // x-GEMM: cx = x@Wx slice (C-init for 4 stages), operand-swapped
      short8 axh0 = ldsA<128>(xbh, l15, lq * 8);
      short8 axh1 = ldsA<128>(xbh, l15, 32 + lq * 8);
      short8 axl0 = ldsA<128>(xbl, l15, lq * 8);
      short8 axl1 = ldsA<128>(xbl, l15, 32 + lq * 8);
      #pragma unroll
      for (int n2 = 0; n2 < 2; ++n2){
        int nblk = dh * 16 + w * 2 + n2;
        int f0 = ((     nblk) * 2) * 64 + lane;
        int f1 = ((64 + nblk) * 2) * 64 + lane;
        short8 wh0 = Wxv[f0], wl0 = Wxv[f0 + 64];
        short8 wh1 = Wxv[f1], wl1 = Wxv[f1 + 64];
        f32x4 c = {0.f, 0.f, 0.f, 0.f};
        c = MFMA(wh0, axh0, c); c = MFMA(wl0, axh0, c); c = MFMA(wh0, axl0, c);
        c = MFMA(wh1, axh1, c); c = MFMA(wl1, axh1, c); c = MFMA(wh1, axl1, c);
        cx[n2] = c;
      }
    }

    #pragma unroll 1
    for (int s = 0; s < 4; ++s){
      const float ts = (s == 0) ? t0 : ((s == 3) ? t1 : t0 + 0.5f * hs);

      // ---- GEMM1: acc = z @ W1[:, slice] + cx, 1-deep weight prefetch ----
      f32x4 acc[2] = {cx[0], cx[1]};
      {
        const int nb0 = dh * 16 + w * 2;
        short8 cwh[2], cwl[2], nwh[2], nwl[2];
        #pragma unroll
        for (int n2 = 0; n2 < 2; ++n2){
          int fi = ((nb0 + n2) * 2) * 64 + lane;
          cwh[n2] = W1v[fi]; cwl[n2] = W1v[fi + 64];
        }
        #pragma unroll 1
        for (int ks = 0; ks < 8; ++ks){
          short8 azh = ldsA<512>(zsh, l15, ks * 32 + lq * 8);
          short8 azl = ldsA<512>(zsl, l15, ks * 32 + lq * 8);
          if (ks < 7){
            #pragma unroll
            for (int n2 = 0; n2 < 2; ++n2){
              int fi = (((ks + 1) * 64 + nb0 + n2) * 2) * 64 + lane;
              nwh[n2] = W1v[fi]; nwl[n2] = W1v[fi + 64];
            }
          }
          #pragma unroll
          for (int n2 = 0; n2 < 2; ++n2){
            acc[n2] = MFMA(cwh[n2], azh, acc[n2]);
            acc[n2] = MFMA(cwl[n2], azh, acc[n2]);
            acc[n2] = MFMA(cwh[n2], azl, acc[n2]);
          }
          cwh[0] = nwh[0]; cwh[1] = nwh[1];
          cwl[0] = nwl[0]; cwl[1] = nwl[1];
        }
      }
      // epilogue: bias + tanh, pack, b64 LDS writes (local h slice)
      #pragma unroll
      for (int n2 = 0; n2 < 2; ++n2){
        int cb = w * 32 + n2 * 16 + lq * 4;
        f32x4 b1v = *reinterpret_cast<const f32x4*>(&b1l[cb]);
        f32x4 wtv = *reinterpret_cast<const f32x4*>(&wtl[cb]);
        float v[4];
        #pragma unroll
        for (int i = 0; i < 4; ++i)
          v[i] = tanh_fast(acc[n2][i] + b1v[i] + ts * wtv[i]);
        unsigned long long hi, lo;
        pack4(v, hi, lo);
        ldsW64<512>(hbh, l15, cb, hi);
        ldsW64<512>(hbl, l15, cb, lo);
      }
      __syncthreads();   // h slice ready

      // ---- GEMM2 partial: weights from the resident register cache ----
      f32x4 acc2[2] = {{0.f,0.f,0.f,0.f}, {0.f,0.f,0.f,0.f}};
      #pragma unroll
      for (int ks = 0; ks < 8; ++ks){
        short8 ahh = ldsA<512>(hbh, l15, ks * 32 + lq * 8);
        short8 ahl = ldsA<512>(hbl, l15, ks * 32 + lq * 8);
        #pragma unroll
        for (int n2 = 0; n2 < 2; ++n2){
          acc2[n2] = MFMA(w2h[ks][n2], ahh, acc2[n2]);
          acc2[n2] = MFMA(w2l[ks][n2], ahh, acc2[n2]);
          acc2[n2] = MFMA(w2h[ks][n2], ahl, acc2[n2]);
        }
      }

      // ---- exchange partials (fragment-flat layout, coalesced, sc0 sc1) ----
      const int g = step * 4 + s;
      float* slot = grpPart + ((g & 1) ? (size_t)PART_FLOATS_PER_SLOT : 0);
      {
        float* dst = slot + dh * 4096;
        #pragma unroll
        for (int n2 = 0; n2 < 2; ++n2)
          #pragma unroll
          for (int i = 0; i < 4; ++i){
            int flat = ((w * 2 + n2) * 4 + i) * 64 + lane;
            st_sc(dst + flat, acc2[n2][i]);
          }
      }
      asm volatile("s_waitcnt vmcnt(0)" ::: "memory");
      __syncthreads();                 // all stores at coherence point
      target += 4;
      if (tid == 0){
        __hip_atomic_fetch_add(myctr, 1u, __ATOMIC_RELAXED, __HIP_MEMORY_SCOPE_AGENT);
        while (__hip_atomic_load(myctr, __ATOMIC_RELAXED, __HIP_MEMORY_SCOPE_AGENT) < target)
          __builtin_amdgcn_s_sleep(1);
      }
      __syncthreads();                 // all 4 partials visible

      // read all 4 slots: 8 contiguous floats per thread per slot
      f32x4 v00, v01, v10, v11, v20, v21, v30, v31;
      {
        const float* pr = slot + tid * 8;
        asm volatile(
          "global_load_dwordx4 %0, %8, off sc0 sc1\n\t"
          "global_load_dwordx4 %1, %9, off sc0 sc1\n\t"
          "global_load_dwordx4 %2, %10, off sc0 sc1\n\t"
          "global_load_dwordx4 %3, %11, off sc0 sc1\n\t"
          "global_load_dwordx4 %4, %12, off sc0 sc1\n\t"
          "global_load_dwordx4 %5, %13, off sc0 sc1\n\t"
          "global_load_dwordx4 %6, %14, off sc0 sc1\n\t"
          "global_load_dwordx4 %7, %15, off sc0 sc1\n\t"
          "s_waitcnt vmcnt(0)"
          : "=&v"(v00), "=&v"(v01), "=&v"(v10), "=&v"(v11),
            "=&v"(v20), "=&v"(v21), "=&v"(v30), "=&v"(v31)
          : "v"(pr), "v"(pr + 4),
            "v"(pr + 4096), "v"(pr + 4100),
            "v"(pr + 8192), "v"(pr + 8196),
            "v"(pr + 12288), "v"(pr + 12292)
          : "memory");
      }
      __builtin_amdgcn_sched_barrier(0);

      // reduce (fixed dh order -> bit-identical across replicas) + RK4
      const float csw = (s == 0 || s == 3) ? 1.f : 2.f;
      const float dc  = (s < 2) ? 0.5f * hs : hs;
      #pragma unroll
      for (int e = 0; e < 8; ++e){
        float s0 = (e < 4) ? v00[e] : v01[e - 4];
        float s1 = (e < 4) ? v10[e] : v11[e - 4];
        float s2 = (e < 4) ? v20[e] : v21[e - 4];
        float s3 = (e < 4) ? v30[e] : v31[e - 4];
        float kv = (((s0 + s1) + s2) + s3) + b2c;
        za[e] += csw * kv;
        float zn;
        if (s < 3){
          zn = zb[e] + dc * kv;
        } else {
          zb[e] += (hs * (1.f / 6.f)) * za[e];
          za[e] = 0.f;
          zn = zb[e];
        }
        unsigned short hh, ll; split_bf(zn, hh, ll);
        ldsW16<512>(zsh, r0r + e, colc, hh);
        ldsW16<512>(zsl, r0r + e, colc, ll);
      }
      __syncthreads();                 // z ready for next stage
    }
  }

  if (dh == 0){
    #pragma unroll
    for (int e = 0; e < 8; ++e)
      out[(rb * 16 + r0r + e) * DZ + colc] = zb[e];
  }
}

// ---------------------------------------------------------------------------
// Fallback: round-2 verified fp32 VALU kernel (no workspace).
// ---------------------------------------------------------------------------
__global__ __launch_bounds__(512) void node_f32(
    const float* __restrict__ z0, const float* __restrict__ tt,
    const float* __restrict__ x,
    const float* __restrict__ W1, const float* __restrict__ Wx,
    const float* __restrict__ wt, const float* __restrict__ b1,
    const float* __restrict__ W2, const float* __restrict__ b2,
    float* __restrict__ out){
  const int wg = blockIdx.x, t = threadIdx.x;
  const int c0 = t, c1 = t + 512, c2 = t & 255, r0 = (t >> 8) * 4;
  __shared__ __align__(16) float zshm[8][260];
  __shared__ __align__(16) float hshm[8][1028];
  __shared__ __align__(16) float xshm[8][68];
  const float b1c0 = b1[c0], b1c1 = b1[c1], wtc0 = wt[c0], wtc1 = wt[c1], b2c = b2[c2];
  float zb[4], za[4];
  #pragma unroll
  for (int i = 0; i < 4; ++i){
    zb[i] = z0[(wg * 8 + r0 + i) * DZ + c2]; za[i] = 0.f; zshm[r0 + i][c2] = zb[i];
  }
  float cx0[8], cx1[8];
  for (int step = 0; step < NSTEP; ++step){
    const float t0 = tt[step], t1 = tt[step + 1], hs = t1 - t0;
    { int xr = t >> 6, xc = t & 63;
      xshm[xr][xc] = x[((size_t)step * 1024 + wg * 8 + xr) * DX + xc]; }
    __syncthreads();
    #pragma unroll
    for (int r = 0; r < 8; ++r){ cx0[r] = 0.f; cx1[r] = 0.f; }
    for (int k0 = 0; k0 < DX; k0 += 4){
      f32x4 xr4[8];
      #pragma unroll
      for (int r = 0; r < 8; ++r) xr4[r] = *(const f32x4*)&xshm[r][k0];
      float w0[4], w1[4];
      #pragma unroll
      for (int j = 0; j < 4; ++j){ w0[j] = Wx[(k0 + j) * DH + c0]; w1[j] = Wx[(k0 + j) * DH + c1]; }
      #pragma unroll
      for (int j = 0; j < 4; ++j)
        #pragma unroll
        for (int r = 0; r < 8; ++r){
          cx0[r] = fmaf(xr4[r][j], w0[j], cx0[r]); cx1[r] = fmaf(xr4[r][j], w1[j], cx1[r]); }
    }
    #pragma unroll 1
    for (int s = 0; s < 4; ++s){
      const float ts = (s == 0) ? t0 : ((s == 3) ? t1 : t0 + 0.5f * hs);
      float a0[8], a1[8];
      #pragma unroll
      for (int r = 0; r < 8; ++r){ a0[r] = cx0[r]; a1[r] = cx1[r]; }
      for (int k0 = 0; k0 < DZ; k0 += 4){
        f32x4 zr4[8];
        #pragma unroll
        for (int r = 0; r < 8; ++r) zr4[r] = *(const f32x4*)&zshm[r][k0];
        float w0[4], w1[4];
        #pragma unroll
        for (int j = 0; j < 4; ++j){ w0[j] = W1[(k0 + j) * DH + c0]; w1[j] = W1[(k0 + j) * DH + c1]; }
        #pragma unroll
        for (int j = 0; j < 4; ++j)
          #pragma unroll
          for (int r = 0; r < 8; ++r){
            a0[r] = fmaf(zr4[r][j], w0[j], a0[r]); a1[r] = fmaf(zr4[r][j], w1[j], a1[r]); }
      }
      const float bias0 = b1c0 + ts * wtc0, bias1 = b1c1 + ts * wtc1;
      #pragma unroll
      for (int r = 0; r < 8; ++r){
        hshm[r][c0] = tanh_fast(a0[r] + bias0); hshm[r][c1] = tanh_fast(a1[r] + bias1); }
      __syncthreads();
      float acc2[4] = {0.f, 0.f, 0.f, 0.f};
      for (int k0 = 0; k0 < DH; k0 += 4){
        f32x4 hr4[4];
        #pragma unroll
        for (int i = 0; i < 4; ++i) hr4[i] = *(const f32x4*)&hshm[r0 + i][k0];
        float w[4];
        #pragma unroll
        for (int j = 0; j < 4; ++j) w[j] = W2[(k0 + j) * DZ + c2];
        #pragma unroll
        for (int j = 0; j < 4; ++j)
          #pragma unroll
          for (int i = 0; i < 4; ++i) acc2[i] = fmaf(hr4[i][j], w[j], acc2[i]);
      }
      const float csw = (s == 0 || s == 3) ? 1.f : 2.f;
      const float dc = (s < 2) ? 0.5f * hs : hs;
      #pragma unroll
      for (int i = 0; i < 4; ++i){
        float kv = acc2[i] + b2c;
        za[i] += csw * kv;
        float zn;
        if (s < 3) zn = zb[i] + dc * kv;
        else { zb[i] += (hs * (1.f / 6.f)) * za[i]; za[i] = 0.f; zn = zb[i]; }
        zshm[r0 + i][c2] = zn;
      }
      __syncthreads();
    }
  }
  #pragma unroll
  for (int i = 0; i < 4; ++i) out[(wg * 8 + r0 + i) * DZ + c2] = zb[i];
}

extern "C" void kernel_launch(void* const* d_in, const int* in_sizes, int n_in,
                              void* d_out, int out_size, void* d_ws, size_t ws_size,
                              hipStream_t stream){
  const float* z0 = (const float*)d_in[0];
  const float* tt = (const float*)d_in[1];
  const float* x  = (const float*)d_in[2];
  const float* W1 = (const float*)d_in[3];
  const float* Wx = (const float*)d_in[4];
  const float* wt = (const float*)d_in[5];
  const float* b1 = (const float*)d_in[6];
  const float* W2 = (const float*)d_in[7];
  const float* b2 = (const float*)d_in[8];

  const size_t wBytes    = (size_t)(524288 + 524288 + 131072) * 2;   // 2359296
  const size_t partOff   = wBytes;
  const size_t partBytes = (size_t)2 * PART_FLOATS_PER_SLOT * 4;     // 8 MB
  const size_t ctrOff    = partOff + partBytes;
  const size_t need      = ctrOff + 64 * 16 * 4;

  if (ws_size >= need){
    short* W1f = (short*)d_ws;
    short* W2f = W1f + 524288;
    short* Wxf = W2f + 524288;
    float* part = (float*)((char*)d_ws + partOff);
    unsigned* ctrs = (unsigned*)((char*)d_ws + ctrOff);
    reformat_weights<<<288, 256, 0, stream>>>(W1, W2, Wx, W1f, W2f, Wxf);
    init_sync<<<1, 64, 0, stream>>>(ctrs);
    node_dh4<<<256, 512, 0, stream>>>(z0, tt, x, W1f, W2f, Wxf, wt, b1, b2,
                                      part, ctrs, (float*)d_out);
  } else {
    node_f32<<<128, 512, 0, stream>>>(z0, tt, x, W1, Wx, wt, b1, W2, b2,
                                      (float*)d_out);
  }
}